// Round 1
// baseline (938.398 us; speedup 1.0000x reference)
//
#include <hip/hip_runtime.h>
#include <math.h>

#define TAU_INV 5.0f   // 1 / 0.2

// ---------------------------------------------------------------------------
// float atomic max via int/uint trick (works for mixed signs, init = -inf)
// ---------------------------------------------------------------------------
__device__ __forceinline__ void atomicMaxFloat(float* addr, float val) {
    if (val >= 0.0f) {
        atomicMax((int*)addr, __float_as_int(val));
    } else {
        atomicMin((unsigned int*)addr, __float_as_uint(val));
    }
}

// ---------------------------------------------------------------------------
// init per-segment max (-inf) and sum (0)
// ---------------------------------------------------------------------------
__global__ void init_seg(float* __restrict__ seg_max, float* __restrict__ seg_sum, int n) {
    int i = blockIdx.x * blockDim.x + threadIdx.x;
    if (i < n) {
        seg_max[i] = -INFINITY;
        seg_sum[i] = 0.0f;
    }
}

// ---------------------------------------------------------------------------
// fp32 GEMM: [Xu; Xi] (rows x D) @ W (D x 128) + bias -> Ou (U x 128), Oi (I x 128)
// 64-row x 128-col tile per block, BK=32, 256 threads, thread = 8 rows x 4 cols
// ---------------------------------------------------------------------------
__global__ __launch_bounds__(256) void gemm_qk(
    const float* __restrict__ Xu, const float* __restrict__ Xi,
    const float* __restrict__ W, const float* __restrict__ bias,
    float* __restrict__ Ou, float* __restrict__ Oi,
    int U, int I, int D)
{
    const int H = 128;
    __shared__ float As[64][33];    // +1 pad
    __shared__ float Bs[32][132];   // +4 pad, keeps float4 alignment

    const int tid  = threadIdx.x;
    const int row0 = blockIdx.x * 64;
    const int tr   = tid >> 5;   // 0..7  -> rows tr*8 .. tr*8+7
    const int tc   = tid & 31;   // 0..31 -> cols tc*4 .. tc*4+3

    float4 acc[8];
#pragma unroll
    for (int i = 0; i < 8; ++i) acc[i] = make_float4(0.f, 0.f, 0.f, 0.f);

    for (int k0 = 0; k0 < D; k0 += 32) {
        // A tile: 64 rows x 32 cols = 512 float4, 2 per thread
#pragma unroll
        for (int t = 0; t < 2; ++t) {
            int idx = tid + t * 256;          // 0..511
            int r = idx >> 3;                 // 0..63
            int c = (idx & 7) * 4;            // 0..28
            int gr = row0 + r;
            float4 v = make_float4(0.f, 0.f, 0.f, 0.f);
            if (gr < U)            v = *(const float4*)&Xu[(size_t)gr * D + k0 + c];
            else if (gr - U < I)   v = *(const float4*)&Xi[(size_t)(gr - U) * D + k0 + c];
            As[r][c + 0] = v.x; As[r][c + 1] = v.y; As[r][c + 2] = v.z; As[r][c + 3] = v.w;
        }
        // B tile: 32 rows x 128 cols = 1024 float4, 4 per thread
#pragma unroll
        for (int t = 0; t < 4; ++t) {
            int idx = tid + t * 256;          // 0..1023
            int r = idx >> 5;                 // 0..31
            int c = (idx & 31) * 4;           // 0..124
            float4 v = *(const float4*)&W[(size_t)(k0 + r) * H + c];
            Bs[r][c + 0] = v.x; Bs[r][c + 1] = v.y; Bs[r][c + 2] = v.z; Bs[r][c + 3] = v.w;
        }
        __syncthreads();
#pragma unroll
        for (int kk = 0; kk < 32; ++kk) {
            float4 bv = *(const float4*)&Bs[kk][tc * 4];
#pragma unroll
            for (int i = 0; i < 8; ++i) {
                float av = As[tr * 8 + i][kk];
                acc[i].x += av * bv.x;
                acc[i].y += av * bv.y;
                acc[i].z += av * bv.z;
                acc[i].w += av * bv.w;
            }
        }
        __syncthreads();
    }

    float4 bb = *(const float4*)&bias[tc * 4];
#pragma unroll
    for (int i = 0; i < 8; ++i) {
        int gr = row0 + tr * 8 + i;
        float4 v = make_float4(acc[i].x + bb.x, acc[i].y + bb.y,
                               acc[i].z + bb.z, acc[i].w + bb.w);
        if (gr < U)           *(float4*)&Ou[(size_t)gr * 128 + tc * 4] = v;
        else if (gr - U < I)  *(float4*)&Oi[(size_t)(gr - U) * 128 + tc * 4] = v;
    }
}

// ---------------------------------------------------------------------------
// per-edge dot(Q[qidx], K[kidx]) (H=128), z = (w - log(-log(noise))) / tau,
// store z, atomic segment max.  32 lanes per edge, float4 per lane.
// ---------------------------------------------------------------------------
__global__ __launch_bounds__(256) void edge_w(
    const float* __restrict__ Q, const float* __restrict__ K,
    const int* __restrict__ qidx, const int* __restrict__ kidx,
    const float* __restrict__ noise,
    float* __restrict__ z, float* __restrict__ seg_max, int E)
{
    const int gtid = blockIdx.x * 256 + threadIdx.x;
    const int eid  = gtid >> 5;
    const int lane = threadIdx.x & 31;
    if (eid >= E) return;

    const int q = qidx[eid];
    const int k = kidx[eid];
    const float4 qv = *(const float4*)&Q[(size_t)q * 128 + lane * 4];
    const float4 kv = *(const float4*)&K[(size_t)k * 128 + lane * 4];
    float d = qv.x * kv.x + qv.y * kv.y + qv.z * kv.z + qv.w * kv.w;
#pragma unroll
    for (int off = 16; off > 0; off >>= 1)
        d += __shfl_xor(d, off);
    if (lane == 0) {
        float g  = __logf(-__logf(noise[eid]));
        float zz = (d - g) * TAU_INV;
        z[eid] = zz;
        atomicMaxFloat(&seg_max[q], zz);
    }
}

// ---------------------------------------------------------------------------
// e = exp(z - max[seg]); in-place; atomic segment sum
// ---------------------------------------------------------------------------
__global__ void edge_exp(float* __restrict__ z, const int* __restrict__ seg,
                         const float* __restrict__ seg_max,
                         float* __restrict__ seg_sum, int E)
{
    int i = blockIdx.x * blockDim.x + threadIdx.x;
    if (i >= E) return;
    int s = seg[i];
    float e = __expf(z[i] - seg_max[s]);
    z[i] = e;
    atomicAdd(&seg_sum[s], e);
}

// ---------------------------------------------------------------------------
// out = e / sum[seg]  (in-place on d_out)
// ---------------------------------------------------------------------------
__global__ void edge_norm(float* __restrict__ ev, const int* __restrict__ seg,
                          const float* __restrict__ seg_sum, int E)
{
    int i = blockIdx.x * blockDim.x + threadIdx.x;
    if (i >= E) return;
    ev[i] = ev[i] / seg_sum[seg[i]];
}

// ---------------------------------------------------------------------------
extern "C" void kernel_launch(void* const* d_in, const int* in_sizes, int n_in,
                              void* d_out, int out_size, void* d_ws, size_t ws_size,
                              hipStream_t stream)
{
    const float* user_embed = (const float*)d_in[0];
    const float* item_embed = (const float*)d_in[1];
    const float* Wq = (const float*)d_in[2];
    const float* bq = (const float*)d_in[3];
    const float* Wk = (const float*)d_in[4];
    const float* bk = (const float*)d_in[5];
    const int* ui_rows   = (const int*)d_in[6];
    const int* ui_cols   = (const int*)d_in[7];
    const float* noise_ui = (const float*)d_in[8];
    const float* noise_iu = (const float*)d_in[9];

    const int H = in_sizes[3];           // 128
    const int D = in_sizes[2] / H;       // 256
    const int U = in_sizes[0] / D;       // 50000
    const int I = in_sizes[1] / D;       // 25000
    const int E = in_sizes[6];           // 1600000
    (void)H;

    // workspace: Qu | Ku | Qi | Ki | seg_max(U+I) | seg_sum(U+I)   (~77 MB)
    float* ws = (float*)d_ws;
    float* Qu = ws;  ws += (size_t)U * 128;
    float* Ku = ws;  ws += (size_t)U * 128;
    float* Qi = ws;  ws += (size_t)I * 128;
    float* Ki = ws;  ws += (size_t)I * 128;
    float* seg_max = ws; ws += (size_t)(U + I);
    float* seg_sum = ws; ws += (size_t)(U + I);
    float* max_u = seg_max;      float* max_i = seg_max + U;
    float* sum_u = seg_sum;      float* sum_i = seg_sum + U;

    // z / e live in d_out across the three edge passes
    float* out_ui = (float*)d_out;
    float* out_iu = out_ui + E;

    const int nseg = U + I;
    init_seg<<<(nseg + 255) / 256, 256, 0, stream>>>(seg_max, seg_sum, nseg);

    const int gblocks = (U + I + 63) / 64;
    gemm_qk<<<gblocks, 256, 0, stream>>>(user_embed, item_embed, Wq, bq, Qu, Qi, U, I, D);
    gemm_qk<<<gblocks, 256, 0, stream>>>(user_embed, item_embed, Wk, bk, Ku, Ki, U, I, D);

    const int eblocks = (int)(((long long)E * 32 + 255) / 256);
    // ui: Q = Qu[rows], K = Ki[cols], segment = rows (users)
    edge_w<<<eblocks, 256, 0, stream>>>(Qu, Ki, ui_rows, ui_cols, noise_ui, out_ui, max_u, E);
    // iu: Q = Qi[cols], K = Ku[rows], segment = cols (items)
    edge_w<<<eblocks, 256, 0, stream>>>(Qi, Ku, ui_cols, ui_rows, noise_iu, out_iu, max_i, E);

    const int sblocks = (E + 255) / 256;
    edge_exp<<<sblocks, 256, 0, stream>>>(out_ui, ui_rows, max_u, sum_u, E);
    edge_exp<<<sblocks, 256, 0, stream>>>(out_iu, ui_cols, max_i, sum_i, E);

    edge_norm<<<sblocks, 256, 0, stream>>>(out_ui, ui_rows, sum_u, E);
    edge_norm<<<sblocks, 256, 0, stream>>>(out_iu, ui_cols, sum_i, E);
}

// Round 2
// 899.674 us; speedup vs baseline: 1.0430x; 1.0430x over previous
//
#include <hip/hip_runtime.h>
#include <math.h>

#define TAU_INV 5.0f   // 1 / 0.2

// ---------------------------------------------------------------------------
// float atomic max via int/uint trick (works for mixed signs, init = -inf)
// ---------------------------------------------------------------------------
__device__ __forceinline__ void atomicMaxFloat(float* addr, float val) {
    if (val >= 0.0f) {
        atomicMax((int*)addr, __float_as_int(val));
    } else {
        atomicMin((unsigned int*)addr, __float_as_uint(val));
    }
}

// ---------------------------------------------------------------------------
// init per-segment max (-inf) and sum (0)
// ---------------------------------------------------------------------------
__global__ void init_seg(float* __restrict__ seg_max, float* __restrict__ seg_sum, int n) {
    int i = blockIdx.x * blockDim.x + threadIdx.x;
    if (i < n) {
        seg_max[i] = -INFINITY;
        seg_sum[i] = 0.0f;
    }
}

// ---------------------------------------------------------------------------
// Merged fp32 GEMM: X = [Xu; Xi] (75000 x 256).
//   Q = X @ Wq + bq -> Qu/Qi,   K = X @ Wk + bk -> Ku/Ki   in ONE kernel
// (A staged once for both). Tile: 64 rows x (128 Q-cols + 128 K-cols), BK=16.
// A is stored TRANSPOSED in LDS (k-major) so the inner loop is pure
// ds_read_b128: 2 broadcast A reads + 2 contiguous B reads per kk against
// 64 v_fmac -> VALU-bound.
// Thread (256/block): tr = tid>>5 (8 row groups x 8 rows), tc = tid&31
// (4 Q-cols tc*4.. and 4 K-cols tc*4..). acc = 8x4x2 = 64 VGPR.
// ---------------------------------------------------------------------------
__global__ __launch_bounds__(256) void gemm_qk_merged(
    const float* __restrict__ Xu, const float* __restrict__ Xi,
    const float* __restrict__ Wq, const float* __restrict__ bq,
    const float* __restrict__ Wk, const float* __restrict__ bk,
    float* __restrict__ Qu, float* __restrict__ Qi,
    float* __restrict__ Ku, float* __restrict__ Ki,
    int U, int I, int D)
{
    // strides padded to a multiple of 4 floats (16 B) so b128 reads stay aligned
    __shared__ float As_t[16][68];    // [k][row], stride 68 -> 16B aligned rows
    __shared__ float Bs_q[16][132];   // [k][col]
    __shared__ float Bs_k[16][132];

    const int tid  = threadIdx.x;
    const int row0 = blockIdx.x * 64;
    const int tr   = tid >> 5;   // 0..7  -> rows tr*8 .. tr*8+7
    const int tc   = tid & 31;   // 0..31 -> cols tc*4 .. tc*4+3

    float4 accq[8], acck[8];
#pragma unroll
    for (int i = 0; i < 8; ++i) {
        accq[i] = make_float4(0.f, 0.f, 0.f, 0.f);
        acck[i] = make_float4(0.f, 0.f, 0.f, 0.f);
    }

    // A-staging indices: 64 rows x 16 k = 256 float4; thread t handles
    // row r = t>>2, k-quad kq = (t&3)*4  (one float4 = 4 consecutive k, 1 row)
    const int ar = tid >> 2;
    const int akq = (tid & 3) * 4;

    for (int k0 = 0; k0 < D; k0 += 16) {
        // ---- stage A (with transpose) ----
        {
            int gr = row0 + ar;
            float4 v = make_float4(0.f, 0.f, 0.f, 0.f);
            if (gr < U)            v = *(const float4*)&Xu[(size_t)gr * D + k0 + akq];
            else if (gr - U < I)   v = *(const float4*)&Xi[(size_t)(gr - U) * D + k0 + akq];
            As_t[akq + 0][ar] = v.x;
            As_t[akq + 1][ar] = v.y;
            As_t[akq + 2][ar] = v.z;
            As_t[akq + 3][ar] = v.w;
        }
        // ---- stage Bq, Bk: 16 rows x 128 cols = 512 float4 each, 2/thread ----
#pragma unroll
        for (int t = 0; t < 2; ++t) {
            int idx = tid + t * 256;          // 0..511
            int r  = idx >> 5;                // 0..15
            int c4 = (idx & 31) * 4;          // 0..124
            float4 vq = *(const float4*)&Wq[(size_t)(k0 + r) * 128 + c4];
            float4 vk = *(const float4*)&Wk[(size_t)(k0 + r) * 128 + c4];
            *(float4*)&Bs_q[r][c4] = vq;
            *(float4*)&Bs_k[r][c4] = vk;
        }
        __syncthreads();

#pragma unroll
        for (int kk = 0; kk < 16; ++kk) {
            float4 a0  = *(const float4*)&As_t[kk][tr * 8];
            float4 a1  = *(const float4*)&As_t[kk][tr * 8 + 4];
            float4 bqv = *(const float4*)&Bs_q[kk][tc * 4];
            float4 bkv = *(const float4*)&Bs_k[kk][tc * 4];
            float a[8] = {a0.x, a0.y, a0.z, a0.w, a1.x, a1.y, a1.z, a1.w};
#pragma unroll
            for (int i = 0; i < 8; ++i) {
                accq[i].x += a[i] * bqv.x;
                accq[i].y += a[i] * bqv.y;
                accq[i].z += a[i] * bqv.z;
                accq[i].w += a[i] * bqv.w;
                acck[i].x += a[i] * bkv.x;
                acck[i].y += a[i] * bkv.y;
                acck[i].z += a[i] * bkv.z;
                acck[i].w += a[i] * bkv.w;
            }
        }
        __syncthreads();
    }

    const float4 bbq = *(const float4*)&bq[tc * 4];
    const float4 bbk = *(const float4*)&bk[tc * 4];
#pragma unroll
    for (int i = 0; i < 8; ++i) {
        int gr = row0 + tr * 8 + i;
        float4 vq = make_float4(accq[i].x + bbq.x, accq[i].y + bbq.y,
                                accq[i].z + bbq.z, accq[i].w + bbq.w);
        float4 vk = make_float4(acck[i].x + bbk.x, acck[i].y + bbk.y,
                                acck[i].z + bbk.z, acck[i].w + bbk.w);
        if (gr < U) {
            *(float4*)&Qu[(size_t)gr * 128 + tc * 4] = vq;
            *(float4*)&Ku[(size_t)gr * 128 + tc * 4] = vk;
        } else if (gr - U < I) {
            *(float4*)&Qi[(size_t)(gr - U) * 128 + tc * 4] = vq;
            *(float4*)&Ki[(size_t)(gr - U) * 128 + tc * 4] = vk;
        }
    }
}

// ---------------------------------------------------------------------------
// per-edge dot(Q[qidx], K[kidx]) (H=128), z = (w - log(-log(noise))) / tau,
// store z, atomic segment max.  32 lanes per edge, float4 per lane.
// ---------------------------------------------------------------------------
__global__ __launch_bounds__(256) void edge_w(
    const float* __restrict__ Q, const float* __restrict__ K,
    const int* __restrict__ qidx, const int* __restrict__ kidx,
    const float* __restrict__ noise,
    float* __restrict__ z, float* __restrict__ seg_max, int E)
{
    const int gtid = blockIdx.x * 256 + threadIdx.x;
    const int eid  = gtid >> 5;
    const int lane = threadIdx.x & 31;
    if (eid >= E) return;

    const int q = qidx[eid];
    const int k = kidx[eid];
    const float4 qv = *(const float4*)&Q[(size_t)q * 128 + lane * 4];
    const float4 kv = *(const float4*)&K[(size_t)k * 128 + lane * 4];
    float d = qv.x * kv.x + qv.y * kv.y + qv.z * kv.z + qv.w * kv.w;
#pragma unroll
    for (int off = 16; off > 0; off >>= 1)
        d += __shfl_xor(d, off);
    if (lane == 0) {
        float g  = __logf(-__logf(noise[eid]));
        float zz = (d - g) * TAU_INV;
        z[eid] = zz;
        atomicMaxFloat(&seg_max[q], zz);
    }
}

// ---------------------------------------------------------------------------
// e = exp(z - max[seg]); in-place; atomic segment sum
// ---------------------------------------------------------------------------
__global__ void edge_exp(float* __restrict__ z, const int* __restrict__ seg,
                         const float* __restrict__ seg_max,
                         float* __restrict__ seg_sum, int E)
{
    int i = blockIdx.x * blockDim.x + threadIdx.x;
    if (i >= E) return;
    int s = seg[i];
    float e = __expf(z[i] - seg_max[s]);
    z[i] = e;
    atomicAdd(&seg_sum[s], e);
}

// ---------------------------------------------------------------------------
// out = e / sum[seg]  (in-place on d_out)
// ---------------------------------------------------------------------------
__global__ void edge_norm(float* __restrict__ ev, const int* __restrict__ seg,
                          const float* __restrict__ seg_sum, int E)
{
    int i = blockIdx.x * blockDim.x + threadIdx.x;
    if (i >= E) return;
    ev[i] = ev[i] / seg_sum[seg[i]];
}

// ---------------------------------------------------------------------------
extern "C" void kernel_launch(void* const* d_in, const int* in_sizes, int n_in,
                              void* d_out, int out_size, void* d_ws, size_t ws_size,
                              hipStream_t stream)
{
    const float* user_embed = (const float*)d_in[0];
    const float* item_embed = (const float*)d_in[1];
    const float* Wq = (const float*)d_in[2];
    const float* bq = (const float*)d_in[3];
    const float* Wk = (const float*)d_in[4];
    const float* bk = (const float*)d_in[5];
    const int* ui_rows   = (const int*)d_in[6];
    const int* ui_cols   = (const int*)d_in[7];
    const float* noise_ui = (const float*)d_in[8];
    const float* noise_iu = (const float*)d_in[9];

    const int H = in_sizes[3];           // 128
    const int D = in_sizes[2] / H;       // 256
    const int U = in_sizes[0] / D;       // 50000
    const int I = in_sizes[1] / D;       // 25000
    const int E = in_sizes[6];           // 1600000
    (void)H;

    // workspace: Qu | Ku | Qi | Ki | seg_max(U+I) | seg_sum(U+I)   (~77 MB)
    float* ws = (float*)d_ws;
    float* Qu = ws;  ws += (size_t)U * 128;
    float* Ku = ws;  ws += (size_t)U * 128;
    float* Qi = ws;  ws += (size_t)I * 128;
    float* Ki = ws;  ws += (size_t)I * 128;
    float* seg_max = ws; ws += (size_t)(U + I);
    float* seg_sum = ws; ws += (size_t)(U + I);
    float* max_u = seg_max;      float* max_i = seg_max + U;
    float* sum_u = seg_sum;      float* sum_i = seg_sum + U;

    // z / e live in d_out across the three edge passes
    float* out_ui = (float*)d_out;
    float* out_iu = out_ui + E;

    const int nseg = U + I;
    init_seg<<<(nseg + 255) / 256, 256, 0, stream>>>(seg_max, seg_sum, nseg);

    const int gblocks = (U + I + 63) / 64;
    gemm_qk_merged<<<gblocks, 256, 0, stream>>>(user_embed, item_embed,
                                                Wq, bq, Wk, bk,
                                                Qu, Qi, Ku, Ki, U, I, D);

    const int eblocks = (int)(((long long)E * 32 + 255) / 256);
    // ui: Q = Qu[rows], K = Ki[cols], segment = rows (users)
    edge_w<<<eblocks, 256, 0, stream>>>(Qu, Ki, ui_rows, ui_cols, noise_ui, out_ui, max_u, E);
    // iu: Q = Qi[cols], K = Ku[rows], segment = cols (items)
    edge_w<<<eblocks, 256, 0, stream>>>(Qi, Ku, ui_cols, ui_rows, noise_iu, out_iu, max_i, E);

    const int sblocks = (E + 255) / 256;
    edge_exp<<<sblocks, 256, 0, stream>>>(out_ui, ui_rows, max_u, sum_u, E);
    edge_exp<<<sblocks, 256, 0, stream>>>(out_iu, ui_cols, max_i, sum_i, E);

    edge_norm<<<sblocks, 256, 0, stream>>>(out_ui, ui_rows, sum_u, E);
    edge_norm<<<sblocks, 256, 0, stream>>>(out_iu, ui_cols, sum_i, E);
}